// Round 1
// baseline (184.721 us; speedup 1.0000x reference)
//
#include <hip/hip_runtime.h>

// ---------------------------------------------------------------------------
// TripletLossWithHardMining  (B=4096, D=1024, fp32 in, fp32 scalar out)
//
//  K1 row_stats : wave-per-row; per-row constants; d_ap, d_an_row; bf16
//                 copies of a,p,n; init hard slots.
//  K2 gemm_mask : FUSED bf16 MFMA GEMM (A.N^T and A.P^T share the A tile),
//                 R5: 8-phase-style pipelined schedule (T3+T4+T5):
//                   BM=256 x BN=128, BK=64, 8 waves, dbuf LDS (128 KB),
//                   per K-tile 4 phases {N,P}x{k0,k1}: ds_read frags ->
//                   stage-next (ph0/1) -> s_barrier -> lgkmcnt(0) ->
//                   setprio(1) 16xMFMA setprio(0) -> s_barrier.
//                   Single s_waitcnt vmcnt(0) per K-tile at phase 3 (loads
//                   issued 2-4 phases earlier -> latency hidden). NO
//                   __syncthreads in the K-loop (its implicit vmcnt(0)
//                   drain was the m97-style stall: MfmaUtil 29%).
//                 global_load_lds(16B) staging + XOR chunk swizzle kept
//                 (slot = chunk ^ (row&7); measured 0 bank conflicts).
//  K3 finalize  : d_an = mean(hard_n), d_pp = mean(hard_p, inf->0),
//                 loss = mean(relu(d_ap - 0.5*d_pp - 0.5*d_an + 1)).
//
//  R4 dead-end note: barrier-free per-wave vmcnt(4) pipeline regressed
//  (184us, MfmaUtil 15%) — doubled VMEM issue + 1-iter prefetch distance.
//  R5 differs: block-lockstep barriers per phase, counted drain once/tile.
// ---------------------------------------------------------------------------

#define NB 4096
#define DIM 1024
#define EPSF 1e-6f
#define D_EPS2 (1024.0f * 1e-6f * 1e-6f)

#define BM 256           // A rows per block tile
#define BN 128           // N / P rows per block tile
#define BK 64            // k-tile (bf16 elems) -> 128 B rows, unpadded

typedef __bf16  bf16x8 __attribute__((ext_vector_type(8)));
typedef float   f32x4  __attribute__((ext_vector_type(4)));

__device__ __forceinline__ unsigned short f2bf(float x) {
    unsigned u = __float_as_uint(x);
    u += 0x7FFFu + ((u >> 16) & 1u);   // round-to-nearest-even
    return (unsigned short)(u >> 16);
}

// async 16B/lane global->LDS; lds base wave-uniform, data lands at base+lane*16
__device__ __forceinline__ void g2l16(const unsigned short* g, unsigned short* l) {
    __builtin_amdgcn_global_load_lds(
        (const __attribute__((address_space(1))) unsigned int*)g,
        (__attribute__((address_space(3))) unsigned int*)l, 16, 0, 0);
}

// stats layout (NB-float slots):
// 0: base_a[i] = |a_i|^2 + 2e*sum_a + D*e^2
// 1: cn[j]     = |n_j|^2 - 2e*sum_n
// 2: cp[j]     = |p_j|^2 - 2e*sum_p
// 3: d_ap   4: d_an_row   5: hard_n bits   6: hard_p bits

// wave-per-row: 1024 blocks x 4 waves; lane handles 4 float4 chunks per matrix
__global__ __launch_bounds__(256) void row_stats_kernel(
    const float* __restrict__ a, const float* __restrict__ p,
    const float* __restrict__ n,
    unsigned short* __restrict__ abf, unsigned short* __restrict__ pbf,
    unsigned short* __restrict__ nbf, float* __restrict__ stats)
{
    const int t    = threadIdx.x;
    const int wave = t >> 6, lane = t & 63;
    const int row  = blockIdx.x * 4 + wave;
    const size_t base = (size_t)row * DIM;

    const float4* a4 = (const float4*)(a + base);
    const float4* p4 = (const float4*)(p + base);
    const float4* n4 = (const float4*)(n + base);

    float v[8] = {0,0,0,0,0,0,0,0};   // sa qa sp qp sn qn dap2 dan2
#pragma unroll
    for (int c = 0; c < 4; c++) {
        const int idx = c * 64 + lane;
        const float4 va = a4[idx];
        const float4 vp = p4[idx];
        const float4 vn = n4[idx];
        const float fa[4] = {va.x, va.y, va.z, va.w};
        const float fp[4] = {vp.x, vp.y, vp.z, vp.w};
        const float fn[4] = {vn.x, vn.y, vn.z, vn.w};
#pragma unroll
        for (int e = 0; e < 4; e++) {
            v[0] += fa[e];           v[1] += fa[e] * fa[e];
            v[2] += fp[e];           v[3] += fp[e] * fp[e];
            v[4] += fn[e];           v[5] += fn[e] * fn[e];
            float dp = fa[e] - fp[e] + EPSF;  v[6] += dp * dp;
            float dn = fa[e] - fn[e] + EPSF;  v[7] += dn * dn;
        }
        ushort4 ba, bp, bn;
        ba.x = f2bf(fa[0]); ba.y = f2bf(fa[1]); ba.z = f2bf(fa[2]); ba.w = f2bf(fa[3]);
        bp.x = f2bf(fp[0]); bp.y = f2bf(fp[1]); bp.z = f2bf(fp[2]); bp.w = f2bf(fp[3]);
        bn.x = f2bf(fn[0]); bn.y = f2bf(fn[1]); bn.z = f2bf(fn[2]); bn.w = f2bf(fn[3]);
        ((ushort4*)(abf + base))[idx] = ba;
        ((ushort4*)(pbf + base))[idx] = bp;
        ((ushort4*)(nbf + base))[idx] = bn;
    }

#pragma unroll
    for (int m = 32; m >= 1; m >>= 1)
#pragma unroll
        for (int q = 0; q < 8; q++) v[q] += __shfl_xor(v[q], m);

    if (lane == 0) {
        stats[0 * NB + row] = v[1] + 2.0f * EPSF * v[0] + D_EPS2;  // base_a
        stats[1 * NB + row] = v[5] - 2.0f * EPSF * v[4];           // cn
        stats[2 * NB + row] = v[3] - 2.0f * EPSF * v[2];           // cp
        stats[3 * NB + row] = sqrtf(v[6]);                         // d_ap
        stats[4 * NB + row] = sqrtf(v[7]);                         // d_an_row
        ((unsigned*)stats)[5 * NB + row] = 0u;                     // hard_n
        ((unsigned*)stats)[6 * NB + row] = 0x7f800000u;            // hard_p
    }
}

// grid (16, 32): block computes A(256 rows) x {N,P}(128 rows) in one pass.
__global__ __launch_bounds__(512, 2) void gemm_mask_kernel(
    const unsigned short* __restrict__ Abf,
    const unsigned short* __restrict__ Nbf,
    const unsigned short* __restrict__ Pbf,
    float* __restrict__ stats)
{
    const int i0 = blockIdx.x * BM;
    const int j0 = blockIdx.y * BN;

    __shared__ unsigned short sA[2][BM * BK];   // 2 x 32 KB
    __shared__ unsigned short sN[2][BN * BK];   // 2 x 16 KB
    __shared__ unsigned short sP[2][BN * BK];   // 2 x 16 KB  => 128 KB total

    const int t    = threadIdx.x;
    const int wave = t >> 6, lane = t & 63;
    const int wm   = wave >> 1, wn = wave & 1;         // 4 x 2 wave grid
    const int quad = lane >> 4, lrow = lane & 15;

    // ---- staging: one g2l round = 512 thr x 16 B = 64 rows x 128 B.
    // thread t -> row srow = t>>3, slot = t&7; slot holds logical chunk
    // slot ^ (srow&7) (pre-swizzled global source, linear LDS dest).
    const int srow = t >> 3;                           // 0..63
    const int slot = t & 7;
    const int kch  = (slot ^ (srow & 7)) * 8;          // elem offset in row
    const unsigned short* gA = Abf + (size_t)(i0 + srow) * DIM + kch;
    const unsigned short* gN = Nbf + (size_t)(j0 + srow) * DIM + kch;
    const unsigned short* gP = Pbf + (size_t)(j0 + srow) * DIM + kch;
    const int lofs = srow * BK + slot * 8;             // elem offset in LDS tile

    // ---- fragment read: logical chunk c = h*4+quad, physical c^(lrow&7)
    const int aoff = (wm * 64 + lrow) * BK;
    const int boff = (wn * 64 + lrow) * BK;
    const int rk0  = ((0 + quad) ^ (lrow & 7)) * 8;    // k-slice 0
    const int rk1  = ((4 + quad) ^ (lrow & 7)) * 8;    // k-slice 1

    f32x4 accN[4][4], accP[4][4];
#pragma unroll
    for (int im = 0; im < 4; im++)
#pragma unroll
        for (int jn = 0; jn < 4; jn++) {
            accN[im][jn] = (f32x4)(0.0f);
            accP[im][jn] = (f32x4)(0.0f);
        }

#define STAGE_A(NBUF, KTN)                                                    \
    _Pragma("unroll")                                                         \
    for (int g = 0; g < 4; g++)                                               \
        g2l16(gA + (size_t)(KTN) + (size_t)(g * 64) * DIM,                    \
              &sA[NBUF][(g * 64) * BK + lofs]);

#define STAGE_NP(NBUF, KTN)                                                   \
    _Pragma("unroll")                                                         \
    for (int g = 0; g < 2; g++) {                                             \
        g2l16(gN + (size_t)(KTN) + (size_t)(g * 64) * DIM,                    \
              &sN[NBUF][(g * 64) * BK + lofs]);                               \
        g2l16(gP + (size_t)(KTN) + (size_t)(g * 64) * DIM,                    \
              &sP[NBUF][(g * 64) * BK + lofs]);                               \
    }

#define MFMA16(ACC, AF, BF)                                                   \
    _Pragma("unroll")                                                         \
    for (int im = 0; im < 4; im++)                                            \
        _Pragma("unroll")                                                     \
        for (int jn = 0; jn < 4; jn++)                                        \
            ACC[im][jn] = __builtin_amdgcn_mfma_f32_16x16x32_bf16(            \
                AF[im], BF[jn], ACC[im][jn], 0, 0, 0);

// one K-tile = 4 phases; A-frags for k0/k1 held in regs across N and P phases.
// Single vmcnt drain per tile, at phase 3 (stages were issued in ph0/ph1).
#define TILE(B, NBUF, KTN, DO_STAGE)                                          \
  {                                                                           \
    bf16x8 af0[4], af1[4], bfr[4];                                            \
    /* phase 0: accN x k0 ; stage next A */                                   \
    _Pragma("unroll")                                                         \
    for (int im = 0; im < 4; im++)                                            \
        af0[im] = *(const bf16x8*)&sA[B][aoff + im * 16 * BK + rk0];          \
    _Pragma("unroll")                                                         \
    for (int jn = 0; jn < 4; jn++)                                            \
        bfr[jn] = *(const bf16x8*)&sN[B][boff + jn * 16 * BK + rk0];          \
    if (DO_STAGE) { STAGE_A(NBUF, KTN); }                                     \
    __builtin_amdgcn_s_barrier();                                             \
    asm volatile("s_waitcnt lgkmcnt(0)" ::: "memory");                        \
    __builtin_amdgcn_s_setprio(1);                                            \
    MFMA16(accN, af0, bfr);                                                   \
    __builtin_amdgcn_s_setprio(0);                                            \
    __builtin_amdgcn_s_barrier();                                             \
    /* phase 1: accN x k1 ; stage next N,P */                                 \
    _Pragma("unroll")                                                         \
    for (int im = 0; im < 4; im++)                                            \
        af1[im] = *(const bf16x8*)&sA[B][aoff + im * 16 * BK + rk1];          \
    _Pragma("unroll")                                                         \
    for (int jn = 0; jn < 4; jn++)                                            \
        bfr[jn] = *(const bf16x8*)&sN[B][boff + jn * 16 * BK + rk1];          \
    if (DO_STAGE) { STAGE_NP(NBUF, KTN); }                                    \
    __builtin_amdgcn_s_barrier();                                             \
    asm volatile("s_waitcnt lgkmcnt(0)" ::: "memory");                        \
    __builtin_amdgcn_s_setprio(1);                                            \
    MFMA16(accN, af1, bfr);                                                   \
    __builtin_amdgcn_s_setprio(0);                                            \
    __builtin_amdgcn_s_barrier();                                             \
    /* phase 2: accP x k0 */                                                  \
    _Pragma("unroll")                                                         \
    for (int jn = 0; jn < 4; jn++)                                            \
        bfr[jn] = *(const bf16x8*)&sP[B][boff + jn * 16 * BK + rk0];          \
    __builtin_amdgcn_s_barrier();                                             \
    asm volatile("s_waitcnt lgkmcnt(0)" ::: "memory");                        \
    __builtin_amdgcn_s_setprio(1);                                            \
    MFMA16(accP, af0, bfr);                                                   \
    __builtin_amdgcn_s_setprio(0);                                            \
    __builtin_amdgcn_s_barrier();                                             \
    /* phase 3: accP x k1 ; drain next-tile staging before buffer swap */     \
    _Pragma("unroll")                                                         \
    for (int jn = 0; jn < 4; jn++)                                            \
        bfr[jn] = *(const bf16x8*)&sP[B][boff + jn * 16 * BK + rk1];          \
    __builtin_amdgcn_s_barrier();                                             \
    asm volatile("s_waitcnt lgkmcnt(0)" ::: "memory");                        \
    __builtin_amdgcn_s_setprio(1);                                            \
    MFMA16(accP, af1, bfr);                                                   \
    __builtin_amdgcn_s_setprio(0);                                            \
    asm volatile("s_waitcnt vmcnt(0)" ::: "memory");                          \
    __builtin_amdgcn_s_barrier();                                             \
  }

    // prologue: stage tile 0 into buf 0
    STAGE_A(0, 0);
    STAGE_NP(0, 0);
    asm volatile("s_waitcnt vmcnt(0)" ::: "memory");
    __builtin_amdgcn_s_barrier();

#pragma unroll 1
    for (int kt = 0; kt < DIM; kt += 2 * BK) {
        TILE(0, 1, kt + BK, 1);
        TILE(1, 0, kt + 2 * BK, (kt + 2 * BK) < DIM);
    }

#undef TILE
#undef MFMA16
#undef STAGE_NP
#undef STAGE_A

    // epilogue: distances + masks + row reduce + atomics
    const float* __restrict__ base_a = stats + 0 * NB;
    const float* __restrict__ cn_v   = stats + 1 * NB;
    const float* __restrict__ cp_v   = stats + 2 * NB;
    const float* __restrict__ d_ap   = stats + 3 * NB;
    const float* __restrict__ d_an   = stats + 4 * NB;
    unsigned* __restrict__ hard_n = ((unsigned*)stats) + 5 * NB;
    unsigned* __restrict__ hard_p = ((unsigned*)stats) + 6 * NB;

#pragma unroll
    for (int im = 0; im < 4; im++) {
#pragma unroll
        for (int r = 0; r < 4; r++) {
            const int gi = i0 + wm * 64 + im * 16 + quad * 4 + r;
            const float cutN = d_ap[gi];
            const float cutP = d_an[gi];
            const float bi   = base_a[gi];
            float bestN = 0.0f;
            float bestP = __uint_as_float(0x7f800000u);
#pragma unroll
            for (int jn = 0; jn < 4; jn++) {
                const int gj = j0 + wn * 64 + jn * 16 + lrow;
                const float dN = sqrtf(fmaxf(bi + cn_v[gj] - 2.0f * accN[im][jn][r], 0.0f));
                const float dP = sqrtf(fmaxf(bi + cp_v[gj] - 2.0f * accP[im][jn][r], 0.0f));
                if (dN < cutN && dN > bestN) bestN = dN;
                if (dP > cutP && dP < bestP) bestP = dP;
            }
#pragma unroll
            for (int m = 1; m < 16; m <<= 1) {
                bestN = fmaxf(bestN, __shfl_xor(bestN, m));
                bestP = fminf(bestP, __shfl_xor(bestP, m));
            }
            if (lrow == 0) {
                const unsigned bn_ = __float_as_uint(bestN);
                const unsigned bp_ = __float_as_uint(bestP);
                if (bn_ != 0u)          atomicMax(hard_n + gi, bn_);
                if (bp_ != 0x7f800000u) atomicMin(hard_p + gi, bp_);
            }
        }
    }
}

__global__ __launch_bounds__(1024) void finalize_kernel(
    const float* __restrict__ stats, float* __restrict__ out)
{
    const unsigned* hard_n = ((const unsigned*)stats) + 5 * NB;
    const unsigned* hard_p = ((const unsigned*)stats) + 6 * NB;
    const float*    d_ap   = stats + 3 * NB;
    const int t = threadIdx.x;
    const int wave = t >> 6, lane = t & 63;
    __shared__ float pn[16], pp[16];
    __shared__ float s_dan, s_dpp;

    float sn = 0.0f, sp = 0.0f;
    for (int i = t; i < NB; i += 1024) {
        sn += __uint_as_float(hard_n[i]);
        const unsigned hp = hard_p[i];
        if (hp != 0x7f800000u) sp += __uint_as_float(hp);
    }
#pragma unroll
    for (int m = 32; m >= 1; m >>= 1) {
        sn += __shfl_xor(sn, m);
        sp += __shfl_xor(sp, m);
    }
    if (lane == 0) { pn[wave] = sn; pp[wave] = sp; }
    __syncthreads();
    if (t == 0) {
        float an = 0.0f, ap = 0.0f;
#pragma unroll
        for (int w = 0; w < 16; w++) { an += pn[w]; ap += pp[w]; }
        s_dan = an / (float)NB;
        s_dpp = ap / (float)NB;
    }
    __syncthreads();
    const float dan = s_dan, dpp = s_dpp;

    float accv = 0.0f;
    for (int i = t; i < NB; i += 1024)
        accv += fmaxf(d_ap[i] - 0.5f * dpp - 0.5f * dan + 1.0f, 0.0f);
#pragma unroll
    for (int m = 32; m >= 1; m >>= 1) accv += __shfl_xor(accv, m);
    if (lane == 0) pn[wave] = accv;
    __syncthreads();
    if (t == 0) {
        float s = 0.0f;
#pragma unroll
        for (int w = 0; w < 16; w++) s += pn[w];
        out[0] = s / (float)NB;
    }
}

extern "C" void kernel_launch(void* const* d_in, const int* in_sizes, int n_in,
                              void* d_out, int out_size, void* d_ws, size_t ws_size,
                              hipStream_t stream) {
    const float* a = (const float*)d_in[0];
    const float* p = (const float*)d_in[1];
    const float* n = (const float*)d_in[2];
    float* out = (float*)d_out;

    // ws layout: abf | pbf | nbf | stats(7*NB floats)  => ~25.3 MB
    unsigned short* abf = (unsigned short*)d_ws;
    unsigned short* pbf = abf + (size_t)NB * DIM;
    unsigned short* nbf = pbf + (size_t)NB * DIM;
    float* stats = (float*)(nbf + (size_t)NB * DIM);

    row_stats_kernel<<<NB / 4, 256, 0, stream>>>(a, p, n, abf, pbf, nbf, stats);

    dim3 grid(NB / BM, NB / BN);
    gemm_mask_kernel<<<grid, 512, 0, stream>>>(abf, nbf, pbf, stats);

    finalize_kernel<<<1, 1024, 0, stream>>>(stats, out);
}